// Round 4
// baseline (105692.236 us; speedup 1.0000x reference)
//
#include <hip/hip_runtime.h>

#define Bq 32
#define Sq 2048
#define Iq 128
#define Hq 512
#define Oq 128
#define NWG 256
#define NT 256
#define SSTRIDE 260                  // dword stride per LDS row (256 + 4 pad)
#define SHBYTES (64 * SSTRIDE * 4)   // 66,560 B dynamic LDS

__device__ __forceinline__ float sigmoidf_(float v) {
    return 1.0f / (1.0f + __expf(-v));
}

// Coherent-at-LLC data access, NO cache-maintenance fences.
__device__ __forceinline__ float ld_coh(const float* p) {
    return __hip_atomic_load(p, __ATOMIC_RELAXED, __HIP_MEMORY_SCOPE_AGENT);
}
__device__ __forceinline__ void st_coh(float* p, float v) {
    __hip_atomic_store(p, v, __ATOMIC_RELAXED, __HIP_MEMORY_SCOPE_AGENT);
}

// ROUND-2 barrier (restored): each block's thread 0 stores epoch to its own
// flag after vmcnt drain; block 0's 256 threads each watch one flag, then
// thread 0 publishes gen; other blocks' thread 0 polls gen. ~511 pollers
// total — no LLC poll storm. Flags monotone, no resets.
__device__ __forceinline__ void gridbar(int* bar, int target) {
    __syncthreads();
    if (threadIdx.x == 0) {
        asm volatile("s_waitcnt vmcnt(0) lgkmcnt(0)" ::: "memory");
        __hip_atomic_store(bar + (blockIdx.x << 1), target, __ATOMIC_RELAXED,
                           __HIP_MEMORY_SCOPE_AGENT);
    }
    int* gen = bar + 768;
    if (blockIdx.x == 0) {
        while (__hip_atomic_load(bar + (threadIdx.x << 1), __ATOMIC_RELAXED,
                                 __HIP_MEMORY_SCOPE_AGENT) < target) {
            __builtin_amdgcn_s_sleep(1);
        }
        __syncthreads();
        if (threadIdx.x == 0) {
            __hip_atomic_store(gen, target, __ATOMIC_RELAXED,
                               __HIP_MEMORY_SCOPE_AGENT);
        }
    } else if (threadIdx.x == 0) {
        while (__hip_atomic_load(gen, __ATOMIC_RELAXED,
                                 __HIP_MEMORY_SCOPE_AGENT) < target) {
            __builtin_amdgcn_s_sleep(1);
        }
    }
    __syncthreads();
}

// Load column tid of 32 rows (row stride 512 floats) into registers.
__device__ __forceinline__ void ld32(float v[32], const float* g, int tid) {
#pragma unroll
    for (int u = 0; u < 32; ++u) v[u] = ld_coh(g + u * 512 + tid);
}
// Write 32 register values to LDS rows [row0, row0+32), column tid.
__device__ __forceinline__ void wr32(float* dst, const float v[32], int tid,
                                     int row0) {
#pragma unroll
    for (int u = 0; u < 32; ++u) dst[(row0 + u) * SSTRIDE + tid] = v[u];
}

// Stage 32 x 128 chunk of IMMUTABLE input x (plain cached loads), coalesced.
// Caller must __syncthreads() after.
__device__ __forceinline__ void stage128p(float* sst, const float* g,
                                          long rowStride) {
    const int tid = threadIdx.x;
    const int k4 = tid & 31, bb = tid >> 5;
#pragma unroll
    for (int u = 0; u < 4; ++u) {
        int b = bb + (u << 3);
        float4 v = *(const float4*)(g + (long)b * rowStride + (k4 << 2));
        *(float4*)(sst + b * SSTRIDE + (k4 << 2)) = v;
    }
}

// K=512 dot: weight row (cached, wave-broadcast) vs staged rows {b, 32+b}.
__device__ __forceinline__ float dot512(const float* sb,
                                        const float* __restrict__ Wrow,
                                        int b) {
    const float* s0 = sb + b * SSTRIDE;
    const float* s1 = sb + (32 + b) * SSTRIDE;
    float a0 = 0.f, a1 = 0.f, a2 = 0.f, a3 = 0.f;
#pragma unroll 8
    for (int k = 0; k < 256; k += 4) {
        float4 w = *(const float4*)(Wrow + k);
        float4 h = *(const float4*)(s0 + k);
        a0 = fmaf(w.x, h.x, a0);
        a1 = fmaf(w.y, h.y, a1);
        a2 = fmaf(w.z, h.z, a2);
        a3 = fmaf(w.w, h.w, a3);
    }
#pragma unroll 8
    for (int k = 0; k < 256; k += 4) {
        float4 w = *(const float4*)(Wrow + 256 + k);
        float4 h = *(const float4*)(s1 + k);
        a0 = fmaf(w.x, h.x, a0);
        a1 = fmaf(w.y, h.y, a1);
        a2 = fmaf(w.z, h.z, a2);
        a3 = fmaf(w.w, h.w, a3);
    }
    return (a0 + a1) + (a2 + a3);
}

// K-length dot (K=128 for x-side), row b only.
__device__ __forceinline__ float dotC(const float* sst,
                                      const float* __restrict__ Wrow, int b,
                                      int K) {
    const float* s = sst + b * SSTRIDE;
    float a0 = 0.f, a1 = 0.f, a2 = 0.f, a3 = 0.f;
#pragma unroll 8
    for (int k = 0; k < K; k += 4) {
        float4 w = *(const float4*)(Wrow + k);
        float4 h = *(const float4*)(s + k);
        a0 = fmaf(w.x, h.x, a0);
        a1 = fmaf(w.y, h.y, a1);
        a2 = fmaf(w.z, h.z, a2);
        a3 = fmaf(w.w, h.w, a3);
    }
    return (a0 + a1) + (a2 + a3);
}

__global__ void bar_init(int* bar) {
    for (int i = threadIdx.x; i < 1024; i += 256) bar[i] = 0;
}

// 2-tick-per-timestep pipelined schedule, balanced, 1 LLC exposure per tick:
//   E(t): wg 0-63  : h0 in regs; A1(t) z0 + C2(t-1) xg1        (2 dots)
//         wg 64-79 : h0+h1 in regs; A1(t) rh0 + Y(t-2)         (2 dots)
//         wg 80-127: h0 in regs; A1(t) rh0                     (1 dot)
//         wg128-255: h0+h1 in regs; C1(t-1) z1/rh1 fused       (2 dots)
//   O(t): wg 0-63  : rh0 in regs; B1(t) h0 update              (1 dot)
//         wg 64-127: rh1 in regs; D1(t-1) h1 update            (1 dot)
//         wg128-223: x cached; X(t+1) xzr0/xg0[par]            (K=128 dots)
__global__ __launch_bounds__(NT, 1) void gru_fused(
    const float* __restrict__ x, const float* __restrict__ h0in,
    const float* __restrict__ Wx0, const float* __restrict__ Wh0,
    const float* __restrict__ bh0, const float* __restrict__ Wx1,
    const float* __restrict__ Wh1, const float* __restrict__ bh1,
    const float* __restrict__ Why, const float* __restrict__ bhy,
    float* __restrict__ out, float* __restrict__ ws) {
    extern __shared__ float sst[];
    const int wg = blockIdx.x;
    const int tid = threadIdx.x;
    int* bar = (int*)(ws + 180224);
    int ep = 0;

    // workspace layout (floats) — all cross-block data, coherent access only
    float* h0 = ws;              // [b*512+j]
    float* h1 = ws + 16384;
    float* xzr0 = ws + 32768;    // [b*1024+jj]
    float* xg0 = ws + 65536;     // 2 x [b*512+j], parity t&1
    float* z0 = ws + 98304;
    float* rh0 = ws + 114688;
    float* z1 = ws + 131072;
    float* rh1 = ws + 147456;
    float* xg1 = ws + 163840;

    // ---- pre-tick: init h0/h1; X(0) into xzr0 + xg0[0] ----
    if (wg < 86) {
        for (int i = wg * NT + tid; i < 2 * Bq * Hq; i += 86 * NT) {
            int b = i >> 10, l = (i >> 9) & 1, j = i & 511;
            st_coh((l ? h1 : h0) + b * Hq + j, h0in[i]);
        }
    } else if (wg >= 128 && wg < 224) {
        stage128p(sst, x, (long)Sq * Iq);  // x_0
        __syncthreads();
        int base = (wg - 128) * 512;
#pragma unroll
        for (int c = 0; c < 2; ++c) {
            int lid = base + c * NT + tid;
            int b = lid & 31, jj = lid >> 5;  // jj in [0,1536)
            float d = dotC(sst, Wx0 + jj * Iq, b, Iq);
            if (jj < 1024)
                st_coh(xzr0 + b * 1024 + jj, d);
            else
                st_coh(xg0 + b * Hq + (jj - 1024), d);  // parity 0
        }
    }
    gridbar(bar, ++ep);

    for (int t = 0; t <= Sq; ++t) {
        // ======== E tick ========
        if (wg < 128) {
            int lid = wg * NT + tid;
            int b = lid & 31, j = lid >> 5;  // j in [0,1024)
            bool doA = (t < Sq);
            bool doC2 = (wg < 64) && (t >= 1);
            bool hasY = (wg >= 64 && wg < 80);
            float v0a[32], v0b[32];
            ld32(v0a, h0, tid);
            ld32(v0b, h0 + 256, tid);
            float v1a[32], v1b[32];
            if (hasY) {  // one exposure: h1 loads issued alongside h0's
                ld32(v1a, h1, tid);
                ld32(v1b, h1 + 256, tid);
            }
            float xv = doA ? ld_coh(xzr0 + b * 1024 + j) : 0.f;
            float bj = doA ? bh0[j] : 0.f;
            wr32(sst, v0a, tid, 0);
            wr32(sst, v0b, tid, 32);
            __syncthreads();
            if (doA) {
                float accA = dot512(sst, Wh0 + j * Hq, b);
                float s = sigmoidf_(xv + accA + bj);
                if (j < Hq) {
                    st_coh(z0 + b * Hq + j, s);
                } else {
                    int jc = j - Hq;
                    float hval = (jc < 256)
                                     ? sst[b * SSTRIDE + jc]
                                     : sst[(32 + b) * SSTRIDE + (jc - 256)];
                    st_coh(rh0 + b * Hq + jc, s * hval);
                }
            }
            if (doC2) {
                float accC = dot512(sst, Wx1 + (2 * Hq + j) * Hq, b);
                st_coh(xg1 + b * Hq + j, accC);
            }
            if (hasY) {
                __syncthreads();  // everyone done reading h0 rows
                wr32(sst, v1a, tid, 0);
                wr32(sst, v1b, tid, 32);
                __syncthreads();
                if (t >= 2) {
                    int lidY = (wg - 64) * NT + tid;  // [0,4096)
                    int bY = lidY & 31, oY = lidY >> 5;
                    float accY = dot512(sst, Why + oY * Hq, bY);
                    out[((size_t)bY * Sq + (t - 2)) * Oq + oY] =
                        accY + bhy[oY];
                }
            }
        } else {
            // C1(t-1): fused z1/r1 (h0 and h1 sides), wg 128-255
            int lid = (wg - 128) * NT + tid;
            int b = lid & 31, j = lid >> 5;  // j in [0,1024)
            bool doC1 = (t >= 1);
            float v0a[32], v0b[32], v1a[32], v1b[32];
            ld32(v0a, h0, tid);
            ld32(v0b, h0 + 256, tid);
            ld32(v1a, h1, tid);
            ld32(v1b, h1 + 256, tid);
            float bj = doC1 ? bh1[j] : 0.f;
            wr32(sst, v0a, tid, 0);
            wr32(sst, v0b, tid, 32);
            __syncthreads();
            float acc1 = doC1 ? dot512(sst, Wx1 + j * Hq, b) : 0.f;
            __syncthreads();
            wr32(sst, v1a, tid, 0);  // overwrite with h1 (already in regs)
            wr32(sst, v1b, tid, 32);
            __syncthreads();
            if (doC1) {
                float acc2 = dot512(sst, Wh1 + j * Hq, b);
                float s = sigmoidf_(acc1 + acc2 + bj);
                if (j < Hq) {
                    st_coh(z1 + b * Hq + j, s);
                } else {
                    int jc = j - Hq;
                    float hval = (jc < 256)
                                     ? sst[b * SSTRIDE + jc]
                                     : sst[(32 + b) * SSTRIDE + (jc - 256)];
                    st_coh(rh1 + b * Hq + jc, s * hval);
                }
            }
        }
        gridbar(bar, ++ep);

        // ======== O tick ========
        if (wg < 64) {
            // B1(t): h0 update
            if (t < Sq) {
                int lid = wg * NT + tid;
                int b = lid & 31, j = lid >> 5;  // [0,512)
                float va[32], vb[32];
                ld32(va, rh0, tid);
                ld32(vb, rh0 + 256, tid);
                float xgv = ld_coh(xg0 + (t & 1) * 16384 + b * Hq + j);
                float zz = ld_coh(z0 + b * Hq + j);
                float hold = ld_coh(h0 + b * Hq + j);
                float bj = bh0[2 * Hq + j];
                wr32(sst, va, tid, 0);
                wr32(sst, vb, tid, 32);
                __syncthreads();
                float acc = dot512(sst, Wh0 + (2 * Hq + j) * Hq, b);
                float g = tanhf(xgv + acc + bj);
                st_coh(h0 + b * Hq + j, zz * hold + (1.f - zz) * g);
            }
        } else if (wg < 128) {
            // D1(t-1): h1 update
            if (t >= 1) {
                int lid = (wg - 64) * NT + tid;
                int b = lid & 31, j = lid >> 5;
                float va[32], vb[32];
                ld32(va, rh1, tid);
                ld32(vb, rh1 + 256, tid);
                float xgv = ld_coh(xg1 + b * Hq + j);
                float zz = ld_coh(z1 + b * Hq + j);
                float hold = ld_coh(h1 + b * Hq + j);
                float bj = bh1[2 * Hq + j];
                wr32(sst, va, tid, 0);
                wr32(sst, vb, tid, 32);
                __syncthreads();
                float acc = dot512(sst, Wh1 + (2 * Hq + j) * Hq, b);
                float g = tanhf(xgv + acc + bj);
                st_coh(h1 + b * Hq + j, zz * hold + (1.f - zz) * g);
            }
        } else if (wg < 224) {
            // X(t+1): xzr0 and xg0[par] for next step
            if (t + 1 < Sq) {
                stage128p(sst, x + (long)(t + 1) * Iq, (long)Sq * Iq);
                __syncthreads();
                int base = (wg - 128) * 512;
                int par = (t + 1) & 1;
#pragma unroll
                for (int c = 0; c < 2; ++c) {
                    int lid = base + c * NT + tid;
                    int b = lid & 31, jj = lid >> 5;
                    float d = dotC(sst, Wx0 + jj * Iq, b, Iq);
                    if (jj < 1024)
                        st_coh(xzr0 + b * 1024 + jj, d);
                    else
                        st_coh(xg0 + par * 16384 + b * Hq + (jj - 1024), d);
                }
            }
        }
        gridbar(bar, ++ep);
    }

    // ---- final tick: hidden state + Y(Sq-1) ----
    if (wg < 128) {
        int i = wg * NT + tid;  // 32768 = B*L*H
        int b = i >> 10, l = (i >> 9) & 1, j = i & 511;
        out[(size_t)Bq * Sq * Oq + i] = ld_coh((l ? h1 : h0) + b * Hq + j);
    } else if (wg >= 240) {
        int lid = (wg - 240) * NT + tid;  // 4096 = B*O
        int b = lid & 31, o = lid >> 5;
        float va[32], vb[32];
        ld32(va, h1, tid);
        ld32(vb, h1 + 256, tid);
        wr32(sst, va, tid, 0);
        wr32(sst, vb, tid, 32);
        __syncthreads();
        float acc = dot512(sst, Why + o * Hq, b);
        out[((size_t)b * Sq + (Sq - 1)) * Oq + o] = acc + bhy[o];
    }
}

extern "C" void kernel_launch(void* const* d_in, const int* in_sizes, int n_in,
                              void* d_out, int out_size, void* d_ws,
                              size_t ws_size, hipStream_t stream) {
    const float* x = (const float*)d_in[0];
    const float* h0in = (const float*)d_in[1];
    const float* Wx0 = (const float*)d_in[2];
    const float* Wh0 = (const float*)d_in[3];
    const float* bh0 = (const float*)d_in[4];
    const float* Wx1 = (const float*)d_in[5];
    const float* Wh1 = (const float*)d_in[6];
    const float* bh1 = (const float*)d_in[7];
    const float* Why = (const float*)d_in[8];
    const float* bhy = (const float*)d_in[9];
    float* out = (float*)d_out;
    float* ws = (float*)d_ws;
    int* bar = (int*)(ws + 180224);

    bar_init<<<1, 256, 0, stream>>>(bar);
    gru_fused<<<dim3(NWG), dim3(NT), SHBYTES, stream>>>(
        x, h0in, Wx0, Wh0, bh0, Wx1, Wh1, bh1, Why, bhy, out, ws);
}

// Round 6
// 56674.176 us; speedup vs baseline: 1.8649x; 1.8649x over previous
//
#include <hip/hip_runtime.h>

#define Bq 32
#define Sq 2048
#define Iq 128
#define Hq 512
#define Oq 128
#define NWG 256
#define NT 256
#define SSTRIDE 260                  // dword stride per LDS row (256 + 4 pad)
#define SHBYTES (64 * SSTRIDE * 4)   // 66,560 B dynamic LDS

__device__ __forceinline__ float sigmoidf_(float v) {
    return 1.0f / (1.0f + __expf(-v));
}

// Coherent-at-LLC data access, NO cache-maintenance fences.
__device__ __forceinline__ float ld_coh(const float* p) {
    return __hip_atomic_load(p, __ATOMIC_RELAXED, __HIP_MEMORY_SCOPE_AGENT);
}
__device__ __forceinline__ void st_coh(float* p, float v) {
    __hip_atomic_store(p, v, __ATOMIC_RELAXED, __HIP_MEMORY_SCOPE_AGENT);
}

// R2 barrier (proven): block's thread 0 stores epoch to its own flag after
// vmcnt drain; block 0's 256 threads each watch one flag, then thread 0
// publishes gen; other blocks' thread 0 polls gen. ~511 pollers total.
__device__ __forceinline__ void gridbar(int* bar, int target) {
    __syncthreads();
    if (threadIdx.x == 0) {
        asm volatile("s_waitcnt vmcnt(0) lgkmcnt(0)" ::: "memory");
        __hip_atomic_store(bar + (blockIdx.x << 1), target, __ATOMIC_RELAXED,
                           __HIP_MEMORY_SCOPE_AGENT);
    }
    int* gen = bar + 768;
    if (blockIdx.x == 0) {
        while (__hip_atomic_load(bar + (threadIdx.x << 1), __ATOMIC_RELAXED,
                                 __HIP_MEMORY_SCOPE_AGENT) < target) {
            __builtin_amdgcn_s_sleep(1);
        }
        __syncthreads();
        if (threadIdx.x == 0) {
            __hip_atomic_store(gen, target, __ATOMIC_RELAXED,
                               __HIP_MEMORY_SCOPE_AGENT);
        }
    } else if (threadIdx.x == 0) {
        while (__hip_atomic_load(gen, __ATOMIC_RELAXED,
                                 __HIP_MEMORY_SCOPE_AGENT) < target) {
            __builtin_amdgcn_s_sleep(1);
        }
    }
    __syncthreads();
}

// Load column tid of 32 rows (row stride 512 floats) into registers.
// MAX 32 live staging floats per thread per batch — spill-safe (R3/R4 lesson).
__device__ __forceinline__ void ld32(float v[32], const float* g, int tid) {
#pragma unroll
    for (int u = 0; u < 32; ++u) v[u] = ld_coh(g + u * 512 + tid);
}
// Write 32 register values to LDS rows [row0, row0+32), column tid.
__device__ __forceinline__ void wr32(float* dst, const float v[32], int tid,
                                     int row0) {
#pragma unroll
    for (int u = 0; u < 32; ++u) dst[(row0 + u) * SSTRIDE + tid] = v[u];
}

// K=256 dot: weight row chunk vs LDS region row b.
__device__ __forceinline__ float dot256(const float* region,
                                        const float* __restrict__ Wrow,
                                        int b) {
    const float* s = region + b * SSTRIDE;
    float a0 = 0.f, a1 = 0.f, a2 = 0.f, a3 = 0.f;
#pragma unroll 8
    for (int k = 0; k < 256; k += 4) {
        float4 w = *(const float4*)(Wrow + k);
        float4 h = *(const float4*)(s + k);
        a0 = fmaf(w.x, h.x, a0);
        a1 = fmaf(w.y, h.y, a1);
        a2 = fmaf(w.z, h.z, a2);
        a3 = fmaf(w.w, h.w, a3);
    }
    return (a0 + a1) + (a2 + a3);
}

// Stage 32 x 128 chunk of IMMUTABLE input x (plain cached loads), coalesced.
// Caller must __syncthreads() after.
__device__ __forceinline__ void stage128p(float* sst, const float* g,
                                          long rowStride) {
    const int tid = threadIdx.x;
    const int k4 = tid & 31, bb = tid >> 5;
#pragma unroll
    for (int u = 0; u < 4; ++u) {
        int b = bb + (u << 3);
        float4 v = *(const float4*)(g + (long)b * rowStride + (k4 << 2));
        *(float4*)(sst + b * SSTRIDE + (k4 << 2)) = v;
    }
}

// K=128 dot (x-side), row b.
__device__ __forceinline__ float dotC(const float* sst,
                                      const float* __restrict__ Wrow, int b,
                                      int K) {
    const float* s = sst + b * SSTRIDE;
    float a0 = 0.f, a1 = 0.f, a2 = 0.f, a3 = 0.f;
#pragma unroll 8
    for (int k = 0; k < K; k += 4) {
        float4 w = *(const float4*)(Wrow + k);
        float4 h = *(const float4*)(s + k);
        a0 = fmaf(w.x, h.x, a0);
        a1 = fmaf(w.y, h.y, a1);
        a2 = fmaf(w.z, h.z, a2);
        a3 = fmaf(w.w, h.w, a3);
    }
    return (a0 + a1) + (a2 + a3);
}

__global__ void bar_init(int* bar) {
    for (int i = threadIdx.x; i < 1024; i += 256) bar[i] = 0;
}

// 2-tick-per-timestep pipelined schedule, ping-pong LDS staging (P=rows 0-31
// holds cols 0-255; Q=rows 32-63 holds cols 256-511), 32-float ld batches:
//   E(t): wg 0-63  : h0; A1(t) z0 + C2(t-1) xg1            (4 dots, 2 chunks)
//         wg 64-79 : h0 then h1; A1(t) rh0 + Y(t-2)        (4 dots, 4 chunks)
//         wg 80-127: h0; A1(t) rh0                         (2 dots, 2 chunks)
//         wg128-255: h0 then h1; C1(t-1) z1/rh1 fused      (4 dots, 4 chunks)
//   O(t): wg 0-63  : rh0; B1(t) h0 update                  (2 dots)
//         wg 64-127: rh1; D1(t-1) h1 update                (2 dots)
//         wg128-223: x; X(t+1) xzr0/xg0[par]               (2 K=128 dots)
__global__ __launch_bounds__(NT, 1) void gru_fused(
    const float* __restrict__ x, const float* __restrict__ h0in,
    const float* __restrict__ Wx0, const float* __restrict__ Wh0,
    const float* __restrict__ bh0, const float* __restrict__ Wx1,
    const float* __restrict__ Wh1, const float* __restrict__ bh1,
    const float* __restrict__ Why, const float* __restrict__ bhy,
    float* __restrict__ out, float* __restrict__ ws) {
    extern __shared__ float sst[];
    float* const Qr = sst + 32 * SSTRIDE;  // Q region base
    const int wg = blockIdx.x;
    const int tid = threadIdx.x;
    int* bar = (int*)(ws + 180224);
    int ep = 0;

    // workspace layout (floats) — all cross-block data, coherent access only
    float* h0 = ws;              // [b*512+j]
    float* h1 = ws + 16384;
    float* xzr0 = ws + 32768;    // [b*1024+jj]
    float* xg0 = ws + 65536;     // 2 x [b*512+j], parity t&1
    float* z0 = ws + 98304;
    float* rh0 = ws + 114688;
    float* z1 = ws + 131072;
    float* rh1 = ws + 147456;
    float* xg1 = ws + 163840;

    // ---- pre-tick: init h0/h1; X(0) into xzr0 + xg0[0] ----
    if (wg < 86) {
        for (int i = wg * NT + tid; i < 2 * Bq * Hq; i += 86 * NT) {
            int b = i >> 10, l = (i >> 9) & 1, j = i & 511;
            st_coh((l ? h1 : h0) + b * Hq + j, h0in[i]);
        }
    } else if (wg >= 128 && wg < 224) {
        stage128p(sst, x, (long)Sq * Iq);  // x_0
        __syncthreads();
        int base = (wg - 128) * 512;
#pragma unroll
        for (int c = 0; c < 2; ++c) {
            int lid = base + c * NT + tid;
            int b = lid & 31, jj = lid >> 5;  // jj in [0,1536)
            float d = dotC(sst, Wx0 + jj * Iq, b, Iq);
            if (jj < 1024)
                st_coh(xzr0 + b * 1024 + jj, d);
            else
                st_coh(xg0 + b * Hq + (jj - 1024), d);  // parity 0
        }
    }
    gridbar(bar, ++ep);

    for (int t = 0; t <= Sq; ++t) {
        // ======== E tick ========
        if (wg < 64 || (wg >= 80 && wg < 128)) {
            // one-source flow: A1(t) on h0 (+C2(t-1) for wg<64)
            int lid = wg * NT + tid;
            int b = lid & 31, j = lid >> 5;  // j in [0,1024)
            bool doA = (t < Sq);
            bool doC2 = (wg < 64) && (t >= 1);
            float va[32], vb[32];
            ld32(va, h0, tid);
            wr32(sst, va, tid, 0);           // P <- h0 cols 0-255
            ld32(vb, h0 + 256, tid);         // in flight under dot P
            float xv = doA ? ld_coh(xzr0 + b * 1024 + j) : 0.f;
            float bj = doA ? bh0[j] : 0.f;
            __syncthreads();                 // S1
            float accA = doA ? dot256(sst, Wh0 + j * Hq, b) : 0.f;
            float accC = doC2 ? dot256(sst, Wx1 + (2 * Hq + j) * Hq, b) : 0.f;
            wr32(sst, vb, tid, 32);          // Q <- h0 cols 256-511
            __syncthreads();                 // S2
            if (doA) accA += dot256(Qr, Wh0 + j * Hq + 256, b);
            if (doC2) accC += dot256(Qr, Wx1 + (2 * Hq + j) * Hq + 256, b);
            if (doA) {
                float s = sigmoidf_(xv + accA + bj);
                if (j < Hq) {
                    st_coh(z0 + b * Hq + j, s);
                } else {
                    int jc = j - Hq;
                    float hval = (jc < 256) ? sst[b * SSTRIDE + jc]
                                            : Qr[b * SSTRIDE + (jc - 256)];
                    st_coh(rh0 + b * Hq + jc, s * hval);
                }
            }
            if (doC2) st_coh(xg1 + b * Hq + j, accC);
        } else {
            // two-source flow: src0=h0, src1=h1; 4 chunks, 4 dots
            bool isY = (wg < 128);  // wg 64-79: A1 rh0 + Y(t-2)
            int lid = isY ? wg * NT + tid : (wg - 128) * NT + tid;
            int b = lid & 31, j = lid >> 5;
            // Y-block identities
            int lidY = (wg - 64) * NT + tid;  // [0,4096)
            int bY = lidY & 31, oY = lidY >> 5;
            bool do1 = isY ? (t < Sq) : (t >= 1);         // first-source dots
            bool do2 = isY ? (t >= 2) : (t >= 1);         // second-source dots
            const float* W1 = isY ? (Wh0 + j * Hq) : (Wx1 + j * Hq);
            const float* W2 = isY ? (Why + oY * Hq) : (Wh1 + j * Hq);
            int b2 = isY ? bY : b;
            float va[32], vb[32];
            ld32(va, h0, tid);
            wr32(sst, va, tid, 0);           // P <- h0c0
            ld32(vb, h0 + 256, tid);
            float bj = 0.f;
            if (isY) bj = do1 ? bh0[j] : 0.f;
            else bj = do1 ? bh1[j] : 0.f;
            float xv = (isY && do1) ? ld_coh(xzr0 + b * 1024 + j) : 0.f;
            float by = (isY && do2) ? bhy[oY] : 0.f;
            __syncthreads();                 // S1
            float acc1 = do1 ? dot256(sst, W1, b) : 0.f;
            wr32(sst, vb, tid, 32);          // Q <- h0c1
            __syncthreads();                 // S2
            ld32(va, h1, tid);               // h1c0 in flight under dot Q
            if (do1) acc1 += dot256(Qr, W1 + 256, b);
            if (isY && do1) {
                // A1 store: uses P/Q h0 values — must precede overwrite
                float s = sigmoidf_(xv + acc1 + bj);
                if (j < Hq) {
                    st_coh(z0 + b * Hq + j, s);
                } else {
                    int jc = j - Hq;
                    float hval = (jc < 256) ? sst[b * SSTRIDE + jc]
                                            : Qr[b * SSTRIDE + (jc - 256)];
                    st_coh(rh0 + b * Hq + jc, s * hval);
                }
            }
            __syncthreads();                 // S3: all done reading P/Q
            wr32(sst, va, tid, 0);           // P <- h1c0
            ld32(vb, h1 + 256, tid);
            __syncthreads();                 // S4
            float acc2 = do2 ? dot256(sst, W2, b2) : 0.f;
            wr32(sst, vb, tid, 32);          // Q <- h1c1
            __syncthreads();                 // S5
            if (do2) acc2 += dot256(Qr, W2 + 256, b2);
            if (isY) {
                if (do2)
                    out[((size_t)bY * Sq + (t - 2)) * Oq + oY] = acc2 + by;
            } else if (do1) {
                // C1 store: z1/rh1 (hval from h1 now in P/Q)
                float s = sigmoidf_(acc1 + acc2 + bj);
                if (j < Hq) {
                    st_coh(z1 + b * Hq + j, s);
                } else {
                    int jc = j - Hq;
                    float hval = (jc < 256) ? sst[b * SSTRIDE + jc]
                                            : Qr[b * SSTRIDE + (jc - 256)];
                    st_coh(rh1 + b * Hq + jc, s * hval);
                }
            }
        }
        gridbar(bar, ++ep);

        // ======== O tick ========
        if (wg < 128) {
            // B1(t) (wg<64, src=rh0) / D1(t-1) (wg 64-127, src=rh1)
            bool isB = (wg < 64);
            bool act = isB ? (t < Sq) : (t >= 1);
            if (act) {
                int lid = (isB ? wg : wg - 64) * NT + tid;
                int b = lid & 31, j = lid >> 5;  // [0,512)
                const float* src = isB ? rh0 : rh1;
                const float* Wg = (isB ? Wh0 : Wh1) + (2 * Hq + j) * Hq;
                float va[32], vb[32];
                ld32(va, src, tid);
                wr32(sst, va, tid, 0);
                ld32(vb, src + 256, tid);
                float xgv = isB ? ld_coh(xg0 + (t & 1) * 16384 + b * Hq + j)
                                : ld_coh(xg1 + b * Hq + j);
                float zz = ld_coh((isB ? z0 : z1) + b * Hq + j);
                float hold = ld_coh((isB ? h0 : h1) + b * Hq + j);
                float bj = (isB ? bh0 : bh1)[2 * Hq + j];
                __syncthreads();
                float acc = dot256(sst, Wg, b);
                wr32(sst, vb, tid, 32);
                __syncthreads();
                acc += dot256(Qr, Wg + 256, b);
                float g = tanhf(xgv + acc + bj);
                st_coh((isB ? h0 : h1) + b * Hq + j,
                       zz * hold + (1.f - zz) * g);
            }
        } else if (wg < 224) {
            // X(t+1): xzr0 and xg0[par] for next step
            if (t + 1 < Sq) {
                stage128p(sst, x + (long)(t + 1) * Iq, (long)Sq * Iq);
                __syncthreads();
                int base = (wg - 128) * 512;
                int par = (t + 1) & 1;
#pragma unroll
                for (int c = 0; c < 2; ++c) {
                    int lid = base + c * NT + tid;
                    int b = lid & 31, jj = lid >> 5;
                    float d = dotC(sst, Wx0 + jj * Iq, b, Iq);
                    if (jj < 1024)
                        st_coh(xzr0 + b * 1024 + jj, d);
                    else
                        st_coh(xg0 + par * 16384 + b * Hq + (jj - 1024), d);
                }
            }
        }
        gridbar(bar, ++ep);
    }

    // ---- final tick: hidden state + Y(Sq-1) ----
    if (wg < 128) {
        int i = wg * NT + tid;  // 32768 = B*L*H
        int b = i >> 10, l = (i >> 9) & 1, j = i & 511;
        out[(size_t)Bq * Sq * Oq + i] = ld_coh((l ? h1 : h0) + b * Hq + j);
    } else if (wg >= 240) {
        int lid = (wg - 240) * NT + tid;  // 4096 = B*O
        int b = lid & 31, o = lid >> 5;
        float va[32], vb[32];
        ld32(va, h1, tid);
        wr32(sst, va, tid, 0);
        ld32(vb, h1 + 256, tid);
        __syncthreads();
        float acc = dot256(sst, Why + o * Hq, b);
        wr32(sst, vb, tid, 32);
        __syncthreads();
        acc += dot256(Qr, Why + o * Hq + 256, b);
        out[((size_t)b * Sq + (Sq - 1)) * Oq + o] = acc + bhy[o];
    }
}

extern "C" void kernel_launch(void* const* d_in, const int* in_sizes, int n_in,
                              void* d_out, int out_size, void* d_ws,
                              size_t ws_size, hipStream_t stream) {
    const float* x = (const float*)d_in[0];
    const float* h0in = (const float*)d_in[1];
    const float* Wx0 = (const float*)d_in[2];
    const float* Wh0 = (const float*)d_in[3];
    const float* bh0 = (const float*)d_in[4];
    const float* Wx1 = (const float*)d_in[5];
    const float* Wh1 = (const float*)d_in[6];
    const float* bh1 = (const float*)d_in[7];
    const float* Why = (const float*)d_in[8];
    const float* bhy = (const float*)d_in[9];
    float* out = (float*)d_out;
    float* ws = (float*)d_ws;
    int* bar = (int*)(ws + 180224);

    bar_init<<<1, 256, 0, stream>>>(bar);
    gru_fused<<<dim3(NWG), dim3(NT), SHBYTES, stream>>>(
        x, h0in, Wx0, Wh0, bh0, Wx1, Wh1, bh1, Why, bhy, out, ws);
}